// Round 5
// baseline (180.339 us; speedup 1.0000x reference)
//
#include <hip/hip_runtime.h>

// LandmarkLoss fused single-kernel, round 5.
// B=4, N=200000, K=64 targets.
// Round-5 changes vs round 4 (inner loop unchanged -- it is near its op floor
// and bit-exact):
//  * Dynamic chunk stealing via per-batch global tickets: removes the
//    3.06-blocks/CU quantization (R4: 15 CUs ran 16 waves while 241 ran 12,
//    a structural 1.33x stretch on the critical path).
//  * Grid = 1024 blocks (4/CU exact), batch = blockIdx & 3; blocks stay
//    batch-pinned so the R4 block-level reduction carries over unchanged.
//  * dl computed as balanced fmin tree (one op less per iteration).

constexpr int KT = 64;
constexpr int P  = 4;
constexpr float DIST_THRESH = 0.1f;
constexpr float W_DIST    = 0.05f;
constexpr float W_CHAMFER = 0.05f;
constexpr float W_SEP     = 0.0005f;
constexpr float PT_SENT = -1e18f;  // dummy-point sentinel (tail lanes)
constexpr float TG_SENT = -1e18f;  // invalid-target sentinel
constexpr float BIGF  = 3.0e38f;
constexpr float WBIAS = 16.0f;     // |t|^2 + WBIAS stored in T.w keeps keyf > 0

__device__ __forceinline__ unsigned umin_(unsigned a, unsigned b) { return a < b ? a : b; }
__device__ __forceinline__ unsigned umax_(unsigned a, unsigned b) { return a > b ? a : b; }

__global__ __launch_bounds__(256, 4)
void landmark_fused(const float* __restrict__ C, const float* __restrict__ F,
                    const float* __restrict__ tC, const int* __restrict__ tF,
                    const int* __restrict__ classes, int n_classes,
                    int B, int N, int cpb,
                    unsigned int* __restrict__ g2p_ws, float* __restrict__ sums,
                    unsigned int* __restrict__ done_ctr,
                    unsigned int* __restrict__ chunk_tick, float* __restrict__ out)
{
    __shared__ float4 tgt2[2 * KT];      // doubled: tgt2[j] == tgt2[j+64]
    __shared__ float gredw[4][KT];
    __shared__ float rs[3][4];
    __shared__ int is_last;
    __shared__ float lossb[4];

    const int tid  = threadIdx.x;
    const int lane = tid & 63;
    const int wib  = tid >> 6;
    const int b    = blockIdx.x & 3;     // batch-pinned blocks, 256 blocks/batch

    // Stage 64 targets: (-2tx,-2ty,-2tz, |t|^2 + WBIAS), sentinel if invalid.
    if (tid < KT) {
        int f = tF[b * KT + tid];
        bool valid = false;
        for (int c = 0; c < n_classes; ++c) valid = valid || (f == classes[c]);
        float x = TG_SENT, y = TG_SENT, z = TG_SENT;
        if (valid) {
            x = tC[(b * KT + tid) * 3 + 0];
            y = tC[(b * KT + tid) * 3 + 1];
            z = tC[(b * KT + tid) * 3 + 2];
        }
        float4 v = make_float4(-2.f * x, -2.f * y, -2.f * z,
                               x * x + y * y + z * z + WBIAS);
        tgt2[tid] = v;
        tgt2[tid + KT] = v;
    }
    __syncthreads();

    const float*  Cb = C + (size_t)b * N * 3;
    const float4* Fb = (const float4*)(F + (size_t)b * N * 4);

    float gmin = BIGF;                       // g2p min (true ld2) for target k == lane
    float dist_acc = 0.f, p2g_acc = 0.f, sep_acc = 0.f;

    for (;;) {
        unsigned cgrab = 0;
        if (lane == 0) cgrab = atomicAdd(&chunk_tick[b], 1u);
        cgrab = (unsigned)__shfl((int)cgrab, 0, 64);
        if (cgrab >= (unsigned)cpb) break;
        const int base = (int)cgrab * (64 * P);

        float px[P], py[P], pz[P], ppm[P], cx[P], cy[P], cz[P], ccm[P], f0[P];
        bool  vp[P];
        #pragma unroll
        for (int p = 0; p < P; ++p) {
            int n = base + p * 64 + lane;
            bool v = (n < N);
            vp[p] = v;
            int ni = v ? n : 0;
            float4 f4 = Fb[ni];
            float X = Cb[3 * ni + 0], Y = Cb[3 * ni + 1], Z = Cb[3 * ni + 2];
            f0[p] = f4.x;
            if (!v) { X = PT_SENT; Y = PT_SENT; Z = PT_SENT; f4.y = f4.z = f4.w = 0.f; }
            px[p] = X;          py[p] = Y;          pz[p] = Z;
            cx[p] = X + f4.y;   cy[p] = Y + f4.z;   cz[p] = Z + f4.w;
            ppm[p] = fmaf(pz[p], pz[p], fmaf(py[p], py[p], px[p] * px[p])) - WBIAS;
            ccm[p] = fmaf(cz[p], cz[p], fmaf(cy[p], cy[p], cx[p] * cx[p])) - WBIAS;
        }

        // keyf = |t|^2 + WBIAS - 2 p.t  (== true pd2 - |p|^2 + WBIAS > 0 for real data)
        // ld2' = |t|^2 + WBIAS - 2 c.t  (true ld2 = ld2' + ccm)
        unsigned k1[P], k2[P];
        float lmin[P];
        #pragma unroll
        for (int p = 0; p < P; ++p) { k1[p] = 0xFFFFFFFFu; k2[p] = 0xFFFFFFFFu; lmin[p] = BIGF; }

        #pragma unroll 8
        for (int i = 0; i < 64; ++i) {
            const float4 T = tgt2[lane + i];         // linear addr, imm offsets
            const unsigned kk = (unsigned)((lane + i) & 63);
            float a[P];
            #pragma unroll
            for (int p = 0; p < P; ++p) {
                float keyf = fmaf(px[p], T.x, fmaf(py[p], T.y, fmaf(pz[p], T.z, T.w)));
                float ld2  = fmaf(cx[p], T.x, fmaf(cy[p], T.y, fmaf(cz[p], T.z, T.w)));
                unsigned key = (__float_as_uint(keyf) & 0xFFFFFFC0u) | kk;
                unsigned hi = umax_(k1[p], key);
                k1[p] = umin_(k1[p], key);
                k2[p] = umin_(k2[p], hi);
                lmin[p] = fminf(lmin[p], ld2);
                a[p] = ld2 + ccm[p];                 // true ld2 for cross-p compare
            }
            float dl = fminf(fminf(a[0], a[1]), fminf(a[2], a[3]));
            float got = __shfl(dl, (lane - i) & 63, 64);
            gmin = fminf(gmin, got);
        }

        #pragma unroll
        for (int p = 0; p < P; ++p) {
            float keyf1 = __uint_as_float(k1[p] & 0xFFFFFFC0u);
            float mind = sqrtf(fmaxf(keyf1 + ppm[p], 0.f));
            bool pm = (mind < DIST_THRESH) && vp[p];
            float tgtv = fminf(mind, 2.0f * DIST_THRESH);
            float diff = f0[p] - tgtv;
            float ad = fabsf(diff);
            float sl1 = (ad < 1.0f) ? 0.5f * diff * diff : (ad - 0.5f);
            if (vp[p]) dist_acc += sl1;
            if (pm) {
                p2g_acc += fmaxf(lmin[p] + ccm[p], 0.f);
                int i1 = (int)(k1[p] & 63u), i2 = (int)(k2[p] & 63u);
                float4 T1 = tgt2[i1], T2 = tgt2[i2];
                float l1sq = fmaf(cx[p], T1.x, fmaf(cy[p], T1.y, fmaf(cz[p], T1.z, T1.w))) + ccm[p];
                float l2sq = fmaf(cx[p], T2.x, fmaf(cy[p], T2.y, fmaf(cz[p], T2.z, T2.w))) + ccm[p];
                sep_acc += sqrtf(fmaxf(l1sq, 0.f) / fmaxf(l2sq, 1e-30f));
            }
        }
    }

    // ---- block-level reduction (all waves in block share batch b) ----
    float v0 = dist_acc, v1 = p2g_acc, v2 = sep_acc;
    #pragma unroll
    for (int o = 32; o > 0; o >>= 1) {
        v0 += __shfl_down(v0, o, 64);
        v1 += __shfl_down(v1, o, 64);
        v2 += __shfl_down(v2, o, 64);
    }
    if (lane == 0) { rs[0][wib] = v0; rs[1][wib] = v1; rs[2][wib] = v2; }
    gredw[wib][lane] = gmin;
    __syncthreads();

    if (tid < 3) {
        float s = rs[tid][0] + rs[tid][1] + rs[tid][2] + rs[tid][3];
        atomicAdd(&sums[tid * 4 + b], s);
    }
    if (tid < KT) {
        float g = fminf(fminf(gredw[0][tid], gredw[1][tid]),
                        fminf(gredw[2][tid], gredw[3][tid]));
        g = fmaxf(g, 0.f);
        // ~bits(g) is monotone decreasing for g>=0: atomicMax accumulates min;
        // init 0 loses to every encode.
        atomicMax(&g2p_ws[b * KT + tid], ~__float_as_uint(g));
    }

    // ---- ticket: last block finalizes ----
    if (tid == 0) {
        __threadfence();
        unsigned int t = atomicAdd(done_ctr, 1u);
        is_last = (t == (unsigned int)(gridDim.x - 1));
    }
    __syncthreads();
    if (!is_last) return;

    {
        const int fb = tid >> 6, fk = tid & 63;
        float g = 0.f, nv = 0.f;
        if (fb < 4) {
            int f = tF[fb * KT + fk];
            bool valid = false;
            for (int c = 0; c < n_classes; ++c) valid = valid || (f == classes[c]);
            if (valid) {
                nv = 1.f;
                unsigned int enc = atomicMax(&g2p_ws[fb * KT + fk], 0u);  // atomic read
                g = __uint_as_float(~enc);
            }
        }
        #pragma unroll
        for (int o = 32; o > 0; o >>= 1) {
            g  += __shfl_down(g, o, 64);
            nv += __shfl_down(nv, o, 64);
        }
        if (fb < 4 && fk == 0) {
            float sd = atomicAdd(&sums[0 * 4 + fb], 0.f);
            float sp = atomicAdd(&sums[1 * 4 + fb], 0.f);
            float ss = atomicAdd(&sums[2 * 4 + fb], 0.f);
            float sep = (nv >= 2.f) ? ss : 0.f;
            lossb[fb] = W_DIST * sd + W_CHAMFER * (sp + g) + W_SEP * sep;
        }
        __syncthreads();
        if (tid == 0) {
            float s = 0.f;
            for (int i = 0; i < 4; ++i) s += lossb[i];
            out[0] = s / 4.0f;
        }
    }
}

extern "C" void kernel_launch(void* const* d_in, const int* in_sizes, int n_in,
                              void* d_out, int out_size, void* d_ws, size_t ws_size,
                              hipStream_t stream)
{
    const float* C       = (const float*)d_in[0];   // (B,N,3)
    const float* F       = (const float*)d_in[1];   // (B,N,4)
    const float* tC      = (const float*)d_in[2];   // (B,K,3)
    const int*   tF      = (const int*)d_in[3];     // (B,K)
    const int*   classes = (const int*)d_in[4];     // (6,)
    const int n_classes = in_sizes[4];
    const int B = 4;
    const int N = in_sizes[0] / (3 * B);            // 200000

    // ws layout: [0,1024) g2p (256 u32), [1024,1072) sums (12 f32),
    //            [1072,1076) done counter, [1088,1104) per-batch chunk tickets
    unsigned int* g2p_ws     = (unsigned int*)d_ws;
    float*        sums       = (float*)((char*)d_ws + 1024);
    unsigned int* done_ctr   = (unsigned int*)((char*)d_ws + 1072);
    unsigned int* chunk_tick = (unsigned int*)((char*)d_ws + 1088);

    hipMemsetAsync(d_ws, 0, 2048, stream);

    const int cpb = (N + 64 * P - 1) / (64 * P);    // 782 chunks per batch
    landmark_fused<<<1024, 256, 0, stream>>>(C, F, tC, tF, classes, n_classes,
                                             B, N, cpb, g2p_ws, sums, done_ctr,
                                             chunk_tick, (float*)d_out);
}

// Round 6
// 108.232 us; speedup vs baseline: 1.6662x; 1.6662x over previous
//
#include <hip/hip_runtime.h>

// LandmarkLoss, round 6. B=4, N=200000, K=64.
// vs R4 (static 784x256, 40us): R5 proved contended-line atomics cost ~36cyc
// serial each; R4's sums/g2p/done-ticket tails ~ 10+ us. Fixes:
//  * g2p and sums replicated x16 (keyed by chunk low bits, line-strided):
//    per-line RMW visits /16 -> tail ~1-2 us.
//  * done-ticket removed; finalize is a separate tiny dispatch.
//  * Occupancy 12.2 -> 24.4 waves/CU with NO extra per-pair ops (R3 trap):
//    each chunk's 64 targets split across 2 waves of a 128-thread block
//    (A: k in [0,32), B: [32,64)). Exact top-2 merge across halves via
//    3 uint min/max on packed keys; merged in LDS once per chunk.
//  * Rotation over 32 targets: 2 bpermutes/iter (lanes l, l+32 share kk).

constexpr int KT = 64;
constexpr int P  = 4;
constexpr int NREP = 16;
constexpr float DIST_THRESH = 0.1f;
constexpr float W_DIST    = 0.05f;
constexpr float W_CHAMFER = 0.05f;
constexpr float W_SEP     = 0.0005f;
constexpr float PT_SENT = -1e18f;  // dummy-point sentinel (tail lanes)
constexpr float TG_SENT = -1e18f;  // invalid-target sentinel
constexpr float BIGF  = 3.0e38f;
constexpr float WBIAS = 16.0f;     // |t|^2 + WBIAS in T.w keeps valid keys > 0

__device__ __forceinline__ unsigned umin_(unsigned a, unsigned b) { return a < b ? a : b; }
__device__ __forceinline__ unsigned umax_(unsigned a, unsigned b) { return a > b ? a : b; }

// ws layout (uints/floats):
//  [0, 16384)      g2p replicas: rep*256 + b*64 + k   (encode ~bits(g), init 0)
//  [16384, 17408)  sums replicas: rep*16 + c*4 + b    (float, init 0)
__global__ __launch_bounds__(128, 6)
void landmark_main(const float* __restrict__ C, const float* __restrict__ F,
                   const float* __restrict__ tC, const int* __restrict__ tF,
                   const int* __restrict__ classes, int n_classes,
                   int N, unsigned int* __restrict__ g2p_rep,
                   float* __restrict__ sums_rep)
{
    __shared__ float4 tgtH2[2][64];   // half h doubled: [h][j]==[h][j+32]
    __shared__ float4 tgtFull[KT];    // full list for epilogue companion lookups
    __shared__ uint4  mK1[64];        // wave A -> B merge buffers
    __shared__ uint4  mK2[64];
    __shared__ float4 mLM[64];

    const int tid   = threadIdx.x;
    const int lane  = tid & 63;
    const int h     = tid >> 6;        // 0: targets [0,32), 1: [32,64)
    const int l31   = lane & 31;
    const int blk   = blockIdx.x;
    const int b     = blk & 3;
    const int chunk = blk >> 2;
    const int rep   = chunk & (NREP - 1);
    const int kbase = h << 5;

    // Stage 64 targets: (-2tx,-2ty,-2tz, |t|^2+WBIAS), sentinel if invalid.
    if (tid < KT) {
        int f = tF[b * KT + tid];
        bool valid = false;
        for (int c = 0; c < n_classes; ++c) valid = valid || (f == classes[c]);
        float x = TG_SENT, y = TG_SENT, z = TG_SENT;
        if (valid) {
            x = tC[(b * KT + tid) * 3 + 0];
            y = tC[(b * KT + tid) * 3 + 1];
            z = tC[(b * KT + tid) * 3 + 2];
        }
        float4 v = make_float4(-2.f * x, -2.f * y, -2.f * z,
                               x * x + y * y + z * z + WBIAS);
        tgtFull[tid] = v;
        int hh = tid >> 5, j = tid & 31;
        tgtH2[hh][j] = v;
        tgtH2[hh][j + 32] = v;
    }
    __syncthreads();

    const float*  Cb = C + (size_t)b * N * 3;
    const float4* Fb = (const float4*)(F + (size_t)b * N * 4);
    const int base = chunk * (64 * P);

    // ---- stage this chunk's 256 points (both waves load the same points) ----
    float px[P], py[P], pz[P], ppm[P], cx[P], cy[P], cz[P], ccm[P], f0[P];
    bool  vp[P];
    #pragma unroll
    for (int p = 0; p < P; ++p) {
        int n = base + p * 64 + lane;
        bool v = (n < N);
        vp[p] = v;
        int ni = v ? n : 0;
        float4 f4 = Fb[ni];
        float X = Cb[3 * ni + 0], Y = Cb[3 * ni + 1], Z = Cb[3 * ni + 2];
        f0[p] = f4.x;
        if (!v) { X = PT_SENT; Y = PT_SENT; Z = PT_SENT; f4.y = f4.z = f4.w = 0.f; }
        px[p] = X;          py[p] = Y;          pz[p] = Z;
        cx[p] = X + f4.y;   cy[p] = Y + f4.z;   cz[p] = Z + f4.w;
        ppm[p] = fmaf(pz[p], pz[p], fmaf(py[p], py[p], px[p] * px[p])) - WBIAS;
        ccm[p] = fmaf(cz[p], cz[p], fmaf(cy[p], cy[p], cx[p] * cx[p])) - WBIAS;
    }

    // keyf = T.w - 2 p.t (true pd2 - |p|^2 + WBIAS, > 0 for valid pairs)
    unsigned k1[P], k2[P];
    float lmin[P];
    #pragma unroll
    for (int p = 0; p < P; ++p) { k1[p] = 0xFFFFFFFFu; k2[p] = 0xFFFFFFFFu; lmin[p] = BIGF; }

    float gmin = BIGF;                     // g2p min for target kbase + (lane&31)
    const float4* TH = tgtH2[h];

    #pragma unroll 8
    for (int i = 0; i < 32; ++i) {
        const float4 T = TH[l31 + i];                 // linear addr, imm offsets
        const unsigned kk = (unsigned)(kbase + ((l31 + i) & 31));
        float a[P];
        #pragma unroll
        for (int p = 0; p < P; ++p) {
            float keyf = fmaf(px[p], T.x, fmaf(py[p], T.y, fmaf(pz[p], T.z, T.w)));
            float ld2  = fmaf(cx[p], T.x, fmaf(cy[p], T.y, fmaf(cz[p], T.z, T.w)));
            unsigned key = (__float_as_uint(keyf) & 0xFFFFFFC0u) | kk;
            unsigned hi = umax_(k1[p], key);
            k1[p] = umin_(k1[p], key);
            k2[p] = umin_(k2[p], hi);
            lmin[p] = fminf(lmin[p], ld2);
            a[p] = ld2 + ccm[p];                      // true ld2 for cross-p compare
        }
        float dl = fminf(fminf(a[0], a[1]), fminf(a[2], a[3]));
        int src = (l31 - i) & 31;                     // contributors: src and src+32
        float g1 = __shfl(dl, src, 64);
        float g2 = __shfl(dl, src + 32, 64);
        gmin = fminf(gmin, fminf(g1, g2));
    }

    // ---- wave A publishes its half's per-point state for the merge ----
    if (h == 0) {
        mK1[lane] = make_uint4(k1[0], k1[1], k1[2], k1[3]);
        mK2[lane] = make_uint4(k2[0], k2[1], k2[2], k2[3]);
        mLM[lane] = make_float4(lmin[0], lmin[1], lmin[2], lmin[3]);
    }
    __syncthreads();

    // ---- per-target g2p -> replicated global (lanes 0..31 own kbase+lane) ----
    if (lane < 32) {
        float g = fmaxf(gmin, 0.f);
        // ~bits(g) monotone decreasing for g>=0: atomicMax == min; init 0 loses.
        atomicMax(&g2p_rep[rep * 256 + b * 64 + kbase + lane], ~__float_as_uint(g));
    }

    if (h == 1) {
        // ---- merge halves + epilogue (wave B only) ----
        uint4 A1 = mK1[lane], A2 = mK2[lane];
        float4 AL = mLM[lane];
        const unsigned a1v[P] = {A1.x, A1.y, A1.z, A1.w};
        const unsigned a2v[P] = {A2.x, A2.y, A2.z, A2.w};
        const float    alv[P] = {AL.x, AL.y, AL.z, AL.w};

        float dist_acc = 0.f, p2g_acc = 0.f, sep_acc = 0.f;
        #pragma unroll
        for (int p = 0; p < P; ++p) {
            unsigned m1 = umin_(a1v[p], k1[p]);
            unsigned m2 = umin_(umax_(a1v[p], k1[p]), umin_(a2v[p], k2[p]));
            float lm = fminf(alv[p], lmin[p]);
            float keyf1 = __uint_as_float(m1 & 0xFFFFFFC0u);
            float mind = sqrtf(fmaxf(keyf1 + ppm[p], 0.f));
            bool pm = (mind < DIST_THRESH) && vp[p];
            float tgtv = fminf(mind, 2.0f * DIST_THRESH);
            float diff = f0[p] - tgtv;
            float ad = fabsf(diff);
            float sl1 = (ad < 1.0f) ? 0.5f * diff * diff : (ad - 0.5f);
            if (vp[p]) dist_acc += sl1;
            if (pm) {
                p2g_acc += fmaxf(lm + ccm[p], 0.f);
                int i1 = (int)(m1 & 63u), i2 = (int)(m2 & 63u);
                float4 T1 = tgtFull[i1], T2 = tgtFull[i2];
                float l1sq = fmaf(cx[p], T1.x, fmaf(cy[p], T1.y, fmaf(cz[p], T1.z, T1.w))) + ccm[p];
                float l2sq = fmaf(cx[p], T2.x, fmaf(cy[p], T2.y, fmaf(cz[p], T2.z, T2.w))) + ccm[p];
                sep_acc += sqrtf(fmaxf(l1sq, 0.f) / fmaxf(l2sq, 1e-30f));
            }
        }

        float v0 = dist_acc, v1 = p2g_acc, v2 = sep_acc;
        #pragma unroll
        for (int o = 32; o > 0; o >>= 1) {
            v0 += __shfl_down(v0, o, 64);
            v1 += __shfl_down(v1, o, 64);
            v2 += __shfl_down(v2, o, 64);
        }
        if (lane == 0) {
            float* sb = sums_rep + rep * 16 + b;
            atomicAdd(sb + 0, v0);
            atomicAdd(sb + 4, v1);
            atomicAdd(sb + 8, v2);
        }
    }
}

__global__ void landmark_finalize(const int* __restrict__ tF, const int* __restrict__ classes,
                                  int n_classes, const unsigned int* __restrict__ g2p_rep,
                                  const float* __restrict__ sums_rep, float* __restrict__ out)
{
    __shared__ float lossb[4];
    const int tid = threadIdx.x;          // 256 threads
    const int b = tid >> 6, k = tid & 63;

    int f = tF[b * KT + k];
    bool valid = false;
    for (int c = 0; c < n_classes; ++c) valid = valid || (f == classes[c]);

    unsigned enc = 0;
    for (int r = 0; r < NREP; ++r) enc = umax_(enc, g2p_rep[r * 256 + b * 64 + k]);
    float g  = valid ? __uint_as_float(~enc) : 0.f;
    float nv = valid ? 1.f : 0.f;

    #pragma unroll
    for (int o = 32; o > 0; o >>= 1) {
        g  += __shfl_down(g, o, 64);
        nv += __shfl_down(nv, o, 64);
    }
    if (k == 0) {
        float sd = 0.f, sp = 0.f, ss = 0.f;
        for (int r = 0; r < NREP; ++r) {
            sd += sums_rep[r * 16 + 0 + b];
            sp += sums_rep[r * 16 + 4 + b];
            ss += sums_rep[r * 16 + 8 + b];
        }
        float sep = (nv >= 2.f) ? ss : 0.f;
        lossb[b] = W_DIST * sd + W_CHAMFER * (sp + g) + W_SEP * sep;
    }
    __syncthreads();
    if (tid == 0)
        out[0] = (lossb[0] + lossb[1] + lossb[2] + lossb[3]) * 0.25f;
}

extern "C" void kernel_launch(void* const* d_in, const int* in_sizes, int n_in,
                              void* d_out, int out_size, void* d_ws, size_t ws_size,
                              hipStream_t stream)
{
    const float* C       = (const float*)d_in[0];   // (B,N,3)
    const float* F       = (const float*)d_in[1];   // (B,N,4)
    const float* tC      = (const float*)d_in[2];   // (B,K,3)
    const int*   tF      = (const int*)d_in[3];     // (B,K)
    const int*   classes = (const int*)d_in[4];     // (6,)
    const int n_classes = in_sizes[4];
    const int B = 4;
    const int N = in_sizes[0] / (3 * B);            // 200000

    unsigned int* g2p_rep  = (unsigned int*)d_ws;
    float*        sums_rep = (float*)((char*)d_ws + NREP * 256 * 4);

    hipMemsetAsync(d_ws, 0, NREP * 256 * 4 + NREP * 16 * 4, stream);

    const int cpb = (N + 64 * P - 1) / (64 * P);    // 782 chunks per batch
    landmark_main<<<cpb * 4, 128, 0, stream>>>(C, F, tC, tF, classes, n_classes,
                                               N, g2p_rep, sums_rep);
    landmark_finalize<<<1, 256, 0, stream>>>(tF, classes, n_classes, g2p_rep,
                                             sums_rep, (float*)d_out);
}

// Round 7
// 99.292 us; speedup vs baseline: 1.8162x; 1.0900x over previous
//
#include <hip/hip_runtime.h>

// LandmarkLoss, round 7. B=4, N=200000, K=64.
// vs R6 (neutral, ~41us): wall-minus-VALUbusy has been a constant ~24us across
// R1/R2/R4/R6 regardless of occupancy -- prime suspect is the per-iteration
// __shfl (ds_bpermute) whose RESULT is consumed in-loop (lgkmcnt wait every
// iteration on the gmin chain). Changes:
//  * g2p delivery via fire-and-forget LDS atomicMin (ds_min_u32, no return,
//    no in-loop wait). One shared g2pLDS[64] per block merges both waves.
//  * XOR rotation kk = l31 ^ i: bijective, distinct addresses per iteration,
//    1 v_xor of address math ((a^b)<<4 == (a<<4)^(b<<4)).
//  * Dot-product pairs (keyf, ld2) computed with packed fp32 FMA
//    (float2 + __builtin_elementwise_fma -> v_pk_fma_f32): 6 FMA -> 3 insts.
//  * Everything else (key packing, top-2 merge across wave halves, x16
//    replicated global atomics, separate finalize dispatch) carried from R6.

constexpr int KT = 64;
constexpr int P  = 4;
constexpr int NREP = 16;
constexpr float DIST_THRESH = 0.1f;
constexpr float W_DIST    = 0.05f;
constexpr float W_CHAMFER = 0.05f;
constexpr float W_SEP     = 0.0005f;
constexpr float PT_SENT = -1e18f;  // dummy-point sentinel (tail lanes)
constexpr float TG_SENT = -1e18f;  // invalid-target sentinel
constexpr float BIGF  = 3.0e38f;
constexpr float WBIAS = 16.0f;     // |t|^2 + WBIAS in T.w keeps valid keys > 0

typedef float f2 __attribute__((ext_vector_type(2)));

__device__ __forceinline__ unsigned umin_(unsigned a, unsigned b) { return a < b ? a : b; }
__device__ __forceinline__ unsigned umax_(unsigned a, unsigned b) { return a > b ? a : b; }

__device__ __forceinline__ f2 pk_fma(f2 a, f2 b, f2 c) {
#if __has_builtin(__builtin_elementwise_fma)
    return __builtin_elementwise_fma(a, b, c);
#else
    f2 r; r.x = fmaf(a.x, b.x, c.x); r.y = fmaf(a.y, b.y, c.y); return r;
#endif
}

// ws layout (uints/floats):
//  [0, 16384)      g2p replicas: rep*256 + b*64 + k   (encode ~bits(g), init 0)
//  [16384, 17408)  sums replicas: rep*16 + c*4 + b    (float, init 0)
__global__ __launch_bounds__(128, 6)
void landmark_main(const float* __restrict__ C, const float* __restrict__ F,
                   const float* __restrict__ tC, const int* __restrict__ tF,
                   const int* __restrict__ classes, int n_classes,
                   int N, unsigned int* __restrict__ g2p_rep,
                   float* __restrict__ sums_rep)
{
    __shared__ float4 tgtH[2][32];     // per-half targets
    __shared__ float4 tgtFull[KT];     // full list for epilogue companion lookups
    __shared__ unsigned g2pLDS[KT];    // shared per-target min (bits of float >= 0)
    __shared__ uint4  mK1[64];         // wave A -> B merge buffers
    __shared__ uint4  mK2[64];
    __shared__ float4 mLM[64];

    const int tid   = threadIdx.x;
    const int lane  = tid & 63;
    const int h     = tid >> 6;        // 0: targets [0,32), 1: [32,64)
    const int l31   = lane & 31;
    const int blk   = blockIdx.x;
    const int b     = blk & 3;
    const int chunk = blk >> 2;
    const int rep   = chunk & (NREP - 1);
    const unsigned kbase = (unsigned)(h << 5);

    // Stage 64 targets: (-2tx,-2ty,-2tz, |t|^2+WBIAS), sentinel if invalid.
    if (tid < KT) {
        int f = tF[b * KT + tid];
        bool valid = false;
        for (int c = 0; c < n_classes; ++c) valid = valid || (f == classes[c]);
        float x = TG_SENT, y = TG_SENT, z = TG_SENT;
        if (valid) {
            x = tC[(b * KT + tid) * 3 + 0];
            y = tC[(b * KT + tid) * 3 + 1];
            z = tC[(b * KT + tid) * 3 + 2];
        }
        float4 v = make_float4(-2.f * x, -2.f * y, -2.f * z,
                               x * x + y * y + z * z + WBIAS);
        tgtFull[tid] = v;
        tgtH[tid >> 5][tid & 31] = v;
        g2pLDS[tid] = 0x7F7FFFFFu;     // FLT_MAX bits
    }
    __syncthreads();

    const float*  Cb = C + (size_t)b * N * 3;
    const float4* Fb = (const float4*)(F + (size_t)b * N * 4);
    const int base = chunk * (64 * P);

    // ---- stage this chunk's 256 points (both waves load the same points) ----
    f2 pcx[P], pcy[P], pcz[P];         // (point, offset-coord) packed pairs
    float ppm[P], ccm[P], f0[P];
    bool  vp[P];
    #pragma unroll
    for (int p = 0; p < P; ++p) {
        int n = base + p * 64 + lane;
        bool v = (n < N);
        vp[p] = v;
        int ni = v ? n : 0;
        float4 f4 = Fb[ni];
        float X = Cb[3 * ni + 0], Y = Cb[3 * ni + 1], Z = Cb[3 * ni + 2];
        f0[p] = f4.x;
        if (!v) { X = PT_SENT; Y = PT_SENT; Z = PT_SENT; f4.y = f4.z = f4.w = 0.f; }
        float cxv = X + f4.y, cyv = Y + f4.z, czv = Z + f4.w;
        pcx[p] = (f2){X, cxv};
        pcy[p] = (f2){Y, cyv};
        pcz[p] = (f2){Z, czv};
        ppm[p] = fmaf(Z, Z, fmaf(Y, Y, X * X)) - WBIAS;
        ccm[p] = fmaf(czv, czv, fmaf(cyv, cyv, cxv * cxv)) - WBIAS;
    }

    // keyf = T.w - 2 p.t (true pd2 - |p|^2 + WBIAS, > 0 for valid pairs)
    unsigned k1[P], k2[P];
    float lmin[P];
    #pragma unroll
    for (int p = 0; p < P; ++p) { k1[p] = 0xFFFFFFFFu; k2[p] = 0xFFFFFFFFu; lmin[p] = BIGF; }

    #pragma unroll 8
    for (int i = 0; i < 32; ++i) {
        const unsigned kk = (unsigned)(l31 ^ i);
        const float4 T = tgtH[h][kk];
        const unsigned tk = kk | kbase;
        const f2 Tx = {T.x, T.x}, Ty = {T.y, T.y}, Tz = {T.z, T.z}, Tw = {T.w, T.w};
        float a0, a1, a2, a3;
        #pragma unroll
        for (int p = 0; p < P; ++p) {
            f2 w = pk_fma(pcx[p], Tx, pk_fma(pcy[p], Ty, pk_fma(pcz[p], Tz, Tw)));
            unsigned key = (__float_as_uint(w.x) & 0xFFFFFFC0u) | tk;
            unsigned hi = umax_(k1[p], key);
            k1[p] = umin_(k1[p], key);
            k2[p] = umin_(k2[p], hi);
            lmin[p] = fminf(lmin[p], w.y);
            float av = w.y + ccm[p];           // true ld2 for cross-p compare
            if (p == 0) a0 = av; else if (p == 1) a1 = av;
            else if (p == 2) a2 = av; else a3 = av;
        }
        float dl = fmaxf(fminf(fminf(a0, a1), fminf(a2, a3)), 0.f);
        atomicMin(&g2pLDS[tk], __float_as_uint(dl));   // ds_min_u32, no return
    }

    // ---- wave A publishes its half's per-point state for the merge ----
    if (h == 0) {
        mK1[lane] = make_uint4(k1[0], k1[1], k1[2], k1[3]);
        mK2[lane] = make_uint4(k2[0], k2[1], k2[2], k2[3]);
        mLM[lane] = make_float4(lmin[0], lmin[1], lmin[2], lmin[3]);
    }
    __syncthreads();   // covers ds_min completion + merge publish

    if (h == 0) {
        // ---- per-target g2p -> replicated global (wave A, one lane per target) ----
        // g2pLDS holds bits(g), g >= 0; ~bits monotone decreasing -> atomicMax == min.
        atomicMax(&g2p_rep[rep * 256 + b * 64 + lane], ~g2pLDS[lane]);
    } else {
        // ---- merge halves + epilogue (wave B only) ----
        uint4 A1 = mK1[lane], A2 = mK2[lane];
        float4 AL = mLM[lane];
        const unsigned a1v[P] = {A1.x, A1.y, A1.z, A1.w};
        const unsigned a2v[P] = {A2.x, A2.y, A2.z, A2.w};
        const float    alv[P] = {AL.x, AL.y, AL.z, AL.w};

        float dist_acc = 0.f, p2g_acc = 0.f, sep_acc = 0.f;
        #pragma unroll
        for (int p = 0; p < P; ++p) {
            unsigned m1 = umin_(a1v[p], k1[p]);
            unsigned m2 = umin_(umax_(a1v[p], k1[p]), umin_(a2v[p], k2[p]));
            float lm = fminf(alv[p], lmin[p]);
            float keyf1 = __uint_as_float(m1 & 0xFFFFFFC0u);
            float mind = sqrtf(fmaxf(keyf1 + ppm[p], 0.f));
            bool pm = (mind < DIST_THRESH) && vp[p];
            float tgtv = fminf(mind, 2.0f * DIST_THRESH);
            float diff = f0[p] - tgtv;
            float ad = fabsf(diff);
            float sl1 = (ad < 1.0f) ? 0.5f * diff * diff : (ad - 0.5f);
            if (vp[p]) dist_acc += sl1;
            if (pm) {
                p2g_acc += fmaxf(lm + ccm[p], 0.f);
                int i1 = (int)(m1 & 63u), i2 = (int)(m2 & 63u);
                float4 T1 = tgtFull[i1], T2 = tgtFull[i2];
                float cxv = pcx[p].y, cyv = pcy[p].y, czv = pcz[p].y;
                float l1sq = fmaf(cxv, T1.x, fmaf(cyv, T1.y, fmaf(czv, T1.z, T1.w))) + ccm[p];
                float l2sq = fmaf(cxv, T2.x, fmaf(cyv, T2.y, fmaf(czv, T2.z, T2.w))) + ccm[p];
                sep_acc += sqrtf(fmaxf(l1sq, 0.f) / fmaxf(l2sq, 1e-30f));
            }
        }

        float v0 = dist_acc, v1 = p2g_acc, v2 = sep_acc;
        #pragma unroll
        for (int o = 32; o > 0; o >>= 1) {
            v0 += __shfl_down(v0, o, 64);
            v1 += __shfl_down(v1, o, 64);
            v2 += __shfl_down(v2, o, 64);
        }
        if (lane == 0) {
            float* sb = sums_rep + rep * 16 + b;
            atomicAdd(sb + 0, v0);
            atomicAdd(sb + 4, v1);
            atomicAdd(sb + 8, v2);
        }
    }
}

__global__ void landmark_finalize(const int* __restrict__ tF, const int* __restrict__ classes,
                                  int n_classes, const unsigned int* __restrict__ g2p_rep,
                                  const float* __restrict__ sums_rep, float* __restrict__ out)
{
    __shared__ float lossb[4];
    const int tid = threadIdx.x;          // 256 threads
    const int b = tid >> 6, k = tid & 63;

    int f = tF[b * KT + k];
    bool valid = false;
    for (int c = 0; c < n_classes; ++c) valid = valid || (f == classes[c]);

    unsigned enc = 0;
    for (int r = 0; r < NREP; ++r) enc = umax_(enc, g2p_rep[r * 256 + b * 64 + k]);
    float g  = valid ? __uint_as_float(~enc) : 0.f;
    float nv = valid ? 1.f : 0.f;

    #pragma unroll
    for (int o = 32; o > 0; o >>= 1) {
        g  += __shfl_down(g, o, 64);
        nv += __shfl_down(nv, o, 64);
    }
    if (k == 0) {
        float sd = 0.f, sp = 0.f, ss = 0.f;
        for (int r = 0; r < NREP; ++r) {
            sd += sums_rep[r * 16 + 0 + b];
            sp += sums_rep[r * 16 + 4 + b];
            ss += sums_rep[r * 16 + 8 + b];
        }
        float sep = (nv >= 2.f) ? ss : 0.f;
        lossb[b] = W_DIST * sd + W_CHAMFER * (sp + g) + W_SEP * sep;
    }
    __syncthreads();
    if (tid == 0)
        out[0] = (lossb[0] + lossb[1] + lossb[2] + lossb[3]) * 0.25f;
}

extern "C" void kernel_launch(void* const* d_in, const int* in_sizes, int n_in,
                              void* d_out, int out_size, void* d_ws, size_t ws_size,
                              hipStream_t stream)
{
    const float* C       = (const float*)d_in[0];   // (B,N,3)
    const float* F       = (const float*)d_in[1];   // (B,N,4)
    const float* tC      = (const float*)d_in[2];   // (B,K,3)
    const int*   tF      = (const int*)d_in[3];     // (B,K)
    const int*   classes = (const int*)d_in[4];     // (6,)
    const int n_classes = in_sizes[4];
    const int B = 4;
    const int N = in_sizes[0] / (3 * B);            // 200000

    unsigned int* g2p_rep  = (unsigned int*)d_ws;
    float*        sums_rep = (float*)((char*)d_ws + NREP * 256 * 4);

    hipMemsetAsync(d_ws, 0, NREP * 256 * 4 + NREP * 16 * 4, stream);

    const int cpb = (N + 64 * P - 1) / (64 * P);    // 782 chunks per batch
    landmark_main<<<cpb * 4, 128, 0, stream>>>(C, F, tC, tF, classes, n_classes,
                                               N, g2p_rep, sums_rep);
    landmark_finalize<<<1, 256, 0, stream>>>(tF, classes, n_classes, g2p_rep,
                                             sums_rep, (float*)d_out);
}